// Round 9
// baseline (98.397 us; speedup 1.0000x reference)
//
#include <hip/hip_runtime.h>

// EdgeEmbedding: B=8, L=256, A=15, K=9, EDGE_SIZE=16 — single fused kernel.
//
// Output layout (all float32, concatenated flat):
//   [0,      30720)  block_id   = i/15
//   [30720,  32768)  batch_id   = i/256
//   [32768, 106496)  edges [2][36864]   (row0 src, row1 dst; intra then inter)
//   [106496,696320)  edge_attr [36864][16]
//
// Round-9 change (round-8 budget: 45 ds_read_b128/thread ~= 7 us chip-wide
// LDS pipe): row-i atoms are block-uniform -> read LDS once (15 b128) and
// pin to SGPRs via readfirstlane; inner FMA uses free SGPR operands.
// Pipeline (unchanged math, f64 ordering identical to round-4 oracle-match):
//   1. f32 min-d^2/candidate: {-2x,-2y,-2z,x2} packing -> 4 VALU/pair.
//   2. Histogram quantile (512 bins on bits>>19), threshold T >= v9.
//   3. Mark d32 <= T + DELTA (DELTA >> 2x f32 err => superset of f64 top-9).
//   4. f64 refine of marked only, per-pair f32 prefilter (EPS guarantees
//      the argmin pair is evaluated in f64).
//   5. f64 rank among same-class marked -> winners write ordered slots.

#define BB   8
#define LL   256
#define AA   15
#define KK   9

#define O_BATCH   30720
#define O_EDGES   32768
#define NE_HALF   18432   // B*L*K
#define NE        36864
#define O_ATTR    106496
#define DELTA     0.005f
#define EPS_PAIR  0.01f
#define HBASE     1904    // (0x3B800000 >> 19): bins start at 2^-8
#define NBIN      512

__device__ __forceinline__ float rfl(float v) {
    return __int_as_float(__builtin_amdgcn_readfirstlane(__float_as_int(v)));
}

__global__ __launch_bounds__(256) void edge_fused_kernel(
    const float* __restrict__ pos,   // [B,L,A,3] f32
    const int*   __restrict__ frag,  // [B,L]
    const float* __restrict__ emb,   // [2,16]
    float*       __restrict__ out)
{
    const int blk = blockIdx.x;      // = b*256 + i
    const int b   = blk >> 8;
    const int i   = blk & 255;
    const int j   = threadIdx.x;     // candidate dst block

    __shared__ float4 sAi4[AA];      // row-i: {-2x, -2y, -2z, |x|^2}
    __shared__ double dAi[AA * 3];   // row-i coords (f64)
    __shared__ double dX2i[AA];      // row-i |x|^2 (f64)
    __shared__ float  sD32[LL];      // f32 min d^2 per candidate
    __shared__ double sD64[LL];      // refined f64 d^2 (marked only)
    __shared__ int    sList[LL];     // (cand<<1)|class
    __shared__ int    sHist[2*NBIN]; // per-class histogram
    __shared__ float  sT[2];         // per-class marking threshold
    __shared__ int    sCnt;

    // ---- fused trivial fills (independent of everything) ----
    if (j < AA)  out[blk * AA + j]  = (float)blk;     // block_id
    if (j == AA) out[O_BATCH + blk] = (float)b;       // batch_id
    {
        int idx = blk * 288 + j;                      // 288 attr elems/block
        out[O_ATTR + idx] = emb[(((idx >> 4) < NE_HALF) ? 0 : 16) + (idx & 15)];
        if (j < 32) {
            int idx2 = idx + 256;
            out[O_ATTR + idx2] = emb[(((idx2 >> 4) < NE_HALF) ? 0 : 16) + (idx2 & 15)];
        }
    }

    // ---- stage row-i atoms; zero hist/cnt; init sD64 ----
    if (j < AA) {
        const float* p = pos + (size_t)blk * 45 + j * 3;
        float x = p[0], y = p[1], z = p[2];
        sAi4[j] = make_float4(-2.0f * x, -2.0f * y, -2.0f * z,
                              x*x + y*y + z*z);
        double dx = (double)x, dy = (double)y, dz = (double)z;
        dAi[3*j] = dx; dAi[3*j+1] = dy; dAi[3*j+2] = dz;
        dX2i[j] = dx*dx + dy*dy + dz*dz;
    }
    #pragma unroll
    for (int q = 0; q < 4; ++q) sHist[j + (q << 8)] = 0;   // 1024 ints
    if (j == 255) sCnt = 0;
    sD64[j] = INFINITY;

    const int ftj  = frag[b * LL + j];
    const int segj = (ftj == 2) ? 1 : ftj;
    const int fti  = frag[blk];                       // uniform
    const int segi = (fti == 2) ? 1 : fti;
    // class: 0 = intra (seg==segi, j!=i), 1 = inter, -1 = self
    const int cls  = (j == i) ? -1 : ((segj == segi) ? 0 : 1);
    __syncthreads();

    // ---- row-i atoms: LDS once -> SGPRs (block-uniform) ----
    float Ax[AA], Ay[AA], Az[AA], Aw[AA];
    #pragma unroll
    for (int a = 0; a < AA; ++a) {
        float4 A = sAi4[a];
        Ax[a] = rfl(A.x); Ay[a] = rfl(A.y);
        Az[a] = rfl(A.z); Aw[a] = rfl(A.w);
    }

    // ---- phase 1: f32 min d^2, 3 chunks of 5 candidate atoms ----
    // inner pair: dp = fma(-2ax,cx, fma(-2ay,cy, fma(-2az,cz, x2a)))
    //             m[q] = fmin(m[q], dp);  d2 = m[q] + c2[q] after a-loop
    const float* pj = pos + (size_t)(b * LL + j) * 45;
    float d32 = INFINITY;
    #pragma unroll 1
    for (int cb = 0; cb < AA; cb += 5) {
        float cx[5], cy[5], cz[5], c2[5], m[5];
        #pragma unroll
        for (int q = 0; q < 5; ++q) {
            cx[q] = pj[3*(cb+q) + 0];
            cy[q] = pj[3*(cb+q) + 1];
            cz[q] = pj[3*(cb+q) + 2];
            c2[q] = cx[q]*cx[q] + cy[q]*cy[q] + cz[q]*cz[q];
            m[q]  = INFINITY;
        }
        #pragma unroll
        for (int a = 0; a < AA; ++a) {
            #pragma unroll
            for (int q = 0; q < 5; ++q) {
                float dp = fmaf(Ax[a], cx[q], fmaf(Ay[a], cy[q],
                            fmaf(Az[a], cz[q], Aw[a])));
                m[q] = fminf(m[q], dp);
            }
        }
        #pragma unroll
        for (int q = 0; q < 5; ++q)
            d32 = fminf(d32, m[q] + c2[q]);
    }
    d32 = fmaxf(d32, 0.0f);
    sD32[j] = d32;

    // ---- phase 2a: histogram (bits>>19 monotone for d32 >= 0) ----
    if (cls >= 0) {
        int bin = (int)(__float_as_uint(d32) >> 19) - HBASE;
        bin = min(NBIN - 1, max(0, bin));
        atomicAdd(&sHist[cls * NBIN + bin], 1);
    }
    __syncthreads();

    // ---- phase 2b: waves 0/1 scan 512 bins (8/lane), publish threshold ----
    if (j < 128) {
        const int lane = j & 63, cw = j >> 6;
        int c[8], s = 0;
        #pragma unroll
        for (int q = 0; q < 8; ++q) {
            c[q] = sHist[cw * NBIN + 8*lane + q];
            s += c[q];
        }
        int cum = s;
        #pragma unroll
        for (int off = 1; off < 64; off <<= 1) {
            int v = __shfl_up(cum, off, 64);
            if (lane >= off) cum += v;
        }
        unsigned long long msk = __ballot(cum >= KK);
        if (msk == 0ull) {                 // degenerate (<9 in class)
            if (lane == 0) sT[cw] = INFINITY;
        } else {
            int f = __builtin_ctzll(msk);
            if (lane == f) {
                int before = cum - s;
                int bin = -1;
                #pragma unroll
                for (int q = 0; q < 8; ++q) {
                    before += c[q];
                    if (bin < 0 && before >= KK) bin = 8*f + q;
                }
                sT[cw] = (bin >= NBIN - 1) ? INFINITY
                       : __uint_as_float((unsigned)(HBASE + bin + 1) << 19);
            }
        }
    }
    __syncthreads();

    // ---- phase 3: mark refine superset ----
    const bool marked = (cls >= 0) && (d32 <= sT[cls] + DELTA);
    if (marked) { int p = atomicAdd(&sCnt, 1); sList[p] = (j << 1) | cls; }
    __syncthreads();
    const int cnt = sCnt;   // ~18-22

    // ---- phase 4: f64 refine of marked (wave/candidate, f32 prefilter) ----
    {
        const int wv = j >> 6, lane = j & 63;
        for (int base = 0; base < cnt; base += 4) {
            int t = base + wv;
            double dmin = INFINITY;
            int cand = -1;
            if (t < cnt) {
                cand = sList[t] >> 1;
                const float thr = sD32[cand] + EPS_PAIR;
                const float* pc = pos + (size_t)(b * LL + cand) * 45;
                #pragma unroll
                for (int s4 = 0; s4 < 4; ++s4) {
                    int p = lane + (s4 << 6);
                    if (p < 225) {
                        int a = p / 15, c = p - a * 15;
                        float cx = pc[3*c], cy = pc[3*c+1], cz = pc[3*c+2];
                        float4 A = sAi4[a];
                        float c2 = cx*cx + cy*cy + cz*cz;
                        float dp = fmaf(A.x, cx, fmaf(A.y, cy,
                                    fmaf(A.z, cz, A.w)));
                        if (dp + c2 <= thr) {          // f64 only near the min
                            double dcx = (double)cx, dcy = (double)cy,
                                   dcz = (double)cz;
                            double dot = dAi[3*a]*dcx + dAi[3*a+1]*dcy
                                       + dAi[3*a+2]*dcz;
                            double d2 = (dX2i[a]
                                       + (dcx*dcx + dcy*dcy + dcz*dcz))
                                       - 2.0 * dot;
                            dmin = fmin(dmin, d2);
                        }
                    }
                }
            }
            #pragma unroll
            for (int off = 1; off < 64; off <<= 1)
                dmin = fmin(dmin, __shfl_xor(dmin, off, 64));
            if (lane == 0 && t < cnt) sD64[cand] = fmax(dmin, 0.0);
        }
    }
    __syncthreads();

    // ---- phase 5: f64 rank among same-class marked; winners write ----
    if (marked) {
        double dj = sD64[j];
        int r = 0;
        for (int t = 0; t < cnt; ++t) {
            int e = sList[t];
            if ((e & 1) == cls) {
                int cand = e >> 1;
                double dc = sD64[cand];
                if (dc < dj || (dc == dj && cand < j)) ++r;
            }
        }
        if (r < KK) {
            int e = (cls == 0 ? 0 : NE_HALF) + blk * KK + r;
            out[O_EDGES + e]      = (float)blk;             // src
            out[O_EDGES + NE + e] = (float)(b * LL + j);    // dst
        }
    }
}

extern "C" void kernel_launch(void* const* d_in, const int* in_sizes, int n_in,
                              void* d_out, int out_size, void* d_ws, size_t ws_size,
                              hipStream_t stream) {
    const float* pos  = (const float*)d_in[0];   // pos_heavyatom [8,256,15,3] f32
    const int*   frag = (const int*)d_in[6];     // fragment_type [8,256] i32
    const float* emb  = (const float*)d_in[7];   // edge_emb [2,16] f32
    float* out = (float*)d_out;

    edge_fused_kernel<<<dim3(BB * LL), dim3(256), 0, stream>>>(pos, frag, emb, out);
}